// Round 1
// baseline (749.721 us; speedup 1.0000x reference)
//
#include <hip/hip_runtime.h>
#include <math.h>

#define T_STEPS 500
#define BATCH   64
#define S_DIM   64
#define A_DIM   16
#define OBS_D   32
#define CTL_D   8
#define H_DIM   30

#define LOG2PI 1.8378770664093453f

__device__ __forceinline__ float wmax(float v){
  #pragma unroll
  for (int o = 32; o > 0; o >>= 1) v = fmaxf(v, __shfl_xor(v, o, 64));
  return v;
}
__device__ __forceinline__ float wsum(float v){
  #pragma unroll
  for (int o = 32; o > 0; o >>= 1) v += __shfl_xor(v, o, 64);
  return v;
}

// ---------------- Bp = softmax(B_logits, -1): 1024 rows of 64 ----------------
__global__ __launch_bounds__(256) void k_bp(const float* __restrict__ Blog,
                                            float* __restrict__ Bp){
  const int row  = blockIdx.x * 4 + (threadIdx.x >> 6);
  const int lane = threadIdx.x & 63;
  float v = Blog[row * 64 + lane];
  float m = wmax(v);
  float e = __expf(v - m);
  float s = wsum(e);
  Bp[row * 64 + lane] = e / s;
}

// ---------------- logp_o: forward substitution per (t,b,k) ----------------
__global__ __launch_bounds__(256) void k_logp_o(const float* __restrict__ o,
                                                const float* __restrict__ mu,
                                                const float* __restrict__ lv,
                                                const float* __restrict__ tl,
                                                float* __restrict__ lo){
  __shared__ __align__(16) float Ls[OBS_D * OBS_D];
  __shared__ __align__(16) float mus[OBS_D];
  __shared__ __align__(16) float dinv_s[OBS_D];
  __shared__ float lvsum_s;
  const int k   = blockIdx.x;
  const int tid = threadIdx.x;
  for (int i = tid; i < OBS_D * OBS_D; i += 256) Ls[i] = tl[k * OBS_D * OBS_D + i];
  if (tid < OBS_D){
    mus[tid]    = mu[k * OBS_D + tid];
    dinv_s[tid] = __expf(-lv[k * OBS_D + tid]);
  }
  if (tid == 0){
    float s = 0.f;
    for (int d = 0; d < OBS_D; ++d) s += lv[k * OBS_D + d];
    lvsum_s = s;
  }
  __syncthreads();

  const int item = blockIdx.y * 256 + tid;   // exactly 125*256 = 32000
  const float* op = o + item * OBS_D;
  float d[OBS_D];
  #pragma unroll
  for (int i = 0; i < OBS_D; i += 4){
    float4 v = *(const float4*)(op + i);
    d[i]   = v.x - mus[i];
    d[i+1] = v.y - mus[i+1];
    d[i+2] = v.z - mus[i+2];
    d[i+3] = v.w - mus[i+3];
  }
  float z[OBS_D];
  float acc = 0.f;
  #pragma unroll
  for (int i = 0; i < OBS_D; ++i){
    float s0 = d[i], s1 = 0.f;
    #pragma unroll
    for (int jj = 0; jj + 1 < i; jj += 2){
      s0 = fmaf(-Ls[i * OBS_D + jj],     z[jj],     s0);
      s1 = fmaf(-Ls[i * OBS_D + jj + 1], z[jj + 1], s1);
    }
    if (i & 1) s0 = fmaf(-Ls[i * OBS_D + i - 1], z[i - 1], s0);
    float zz = (s0 + s1) * dinv_s[i];
    z[i] = zz;
    acc  = fmaf(zz, zz, acc);
  }
  lo[item * S_DIM + k] = -0.5f * acc - lvsum_s - 0.5f * OBS_D * LOG2PI;
}

// ---------------- logp_u + p_a per (t,b) ----------------
__global__ __launch_bounds__(256) void k_logp_u(const float* __restrict__ u,
                                                const float* __restrict__ mu,
                                                const float* __restrict__ lv,
                                                const float* __restrict__ tl,
                                                float* __restrict__ lup,
                                                float* __restrict__ pap){
  __shared__ __align__(16) float Ls[A_DIM][CTL_D * CTL_D];
  __shared__ float mus[A_DIM][CTL_D], dinvv[A_DIM][CTL_D], lvs[A_DIM];
  const int tid = threadIdx.x;
  for (int i = tid; i < A_DIM * CTL_D * CTL_D; i += 256) Ls[i >> 6][i & 63] = tl[i];
  if (tid < A_DIM * CTL_D){
    int a = tid >> 3, dd = tid & 7;
    mus[a][dd]   = mu[tid];
    dinvv[a][dd] = __expf(-lv[tid]);
  }
  if (tid < A_DIM){
    float s = 0.f;
    for (int dd = 0; dd < CTL_D; ++dd) s += lv[tid * CTL_D + dd];
    lvs[tid] = s;
  }
  __syncthreads();

  const int item = blockIdx.x * 256 + tid;   // 125*256 = 32000
  const float* up = u + item * CTL_D;
  float uu[CTL_D];
  #pragma unroll
  for (int i = 0; i < CTL_D; i += 4){
    float4 v = *(const float4*)(up + i);
    uu[i] = v.x; uu[i+1] = v.y; uu[i+2] = v.z; uu[i+3] = v.w;
  }
  float lp[A_DIM];
  #pragma unroll
  for (int a = 0; a < A_DIM; ++a){
    float z[CTL_D];
    float acc = 0.f;
    #pragma unroll
    for (int i = 0; i < CTL_D; ++i){
      float s = uu[i] - mus[a][i];
      #pragma unroll
      for (int jj = 0; jj < i; ++jj) s = fmaf(-Ls[a][i * CTL_D + jj], z[jj], s);
      z[i] = s * dinvv[a][i];
      acc  = fmaf(z[i], z[i], acc);
    }
    lp[a] = -0.5f * acc - lvs[a] - 0.5f * CTL_D * LOG2PI;
  }
  float m = -1e30f;
  #pragma unroll
  for (int a = 0; a < A_DIM; ++a) m = fmaxf(m, lp[a]);
  float e[A_DIM], se = 0.f;
  #pragma unroll
  for (int a = 0; a < A_DIM; ++a){ e[a] = __expf(lp[a] - m); se += e[a]; }
  float inv = 1.f / se;
  #pragma unroll
  for (int a = 0; a < A_DIM; ++a){
    lup[item * A_DIM + a] = lp[a];
    pap[item * A_DIM + a] = e[a] * inv;
  }
}

// ---------------- VI: Q[a,s] (single block) ----------------
__global__ __launch_bounds__(256, 1) void k_vi(const float* __restrict__ Bp,
                                               const float* __restrict__ obs_lv,
                                               const float* __restrict__ Clog,
                                               const float* __restrict__ tau,
                                               float* __restrict__ Qout){
  const int tid  = threadIdx.x;
  const int lane = tid & 63;
  __shared__ __align__(16) float Vs[S_DIM];
  __shared__ __align__(16) float Qlds[A_DIM][S_DIM];
  __shared__ float hs[H_DIM];

  // sum_j ln Cp[j] (wave-uniform scalar, every wave computes it)
  float c  = Clog[lane];
  float cm = wmax(c);
  float cs = wsum(__expf(c - cm));
  float lseC = cm + __logf(cs);
  float sumLnCp = wsum(c) - 64.f * lseC;

  // Poisson horizon weights (wave 0)
  if (tid < 64){
    float t0   = tau[0];
    float rate = __expf(t0);
    float lg = 0.f;
    for (int i = 2; i <= lane; ++i) lg += __logf((float)i);
    float lh = (lane < H_DIM) ? ((float)lane * t0 - rate - lg) : -1e30f;
    float m  = wmax(lh);
    float e  = (lane < H_DIM) ? __expf(lh - m) : 0.f;
    float s  = wsum(e);
    if (lane < H_DIM) hs[lane] = e / s;
  }

  // Bp rows in registers + R
  float4 Br[4][16];
  float R[4], Qc[4], Qa[4];
  const int r0 = tid * 4;
  #pragma unroll
  for (int rr = 0; rr < 4; ++rr){
    const float* p = Bp + (r0 + rr) * 64;
    float negentA = 0.f, negentB = 0.f;
    #pragma unroll
    for (int q = 0; q < 16; ++q){
      float4 v = *(const float4*)(p + 4 * q);
      Br[rr][q] = v;
      negentA = fmaf(v.x, __logf(v.x), fmaf(v.y, __logf(v.y), negentA));
      negentB = fmaf(v.z, __logf(v.z), fmaf(v.w, __logf(v.w), negentB));
    }
    int s = (r0 + rr) & 63;
    float oe = 0.f;
    const float* lvp = obs_lv + s * OBS_D;
    #pragma unroll
    for (int d = 0; d < OBS_D; d += 4){
      float4 v = *(const float4*)(lvp + d);
      oe += v.x + v.y + v.z + v.w;
    }
    oe += 0.5f * OBS_D * (1.f + LOG2PI);
    R[rr]  = -(negentA + negentB) + sumLnCp - oe;
    Qc[rr] = R[rr];
  }
  __syncthreads();
  #pragma unroll
  for (int rr = 0; rr < 4; ++rr) Qa[rr] = hs[0] * R[rr];

  const int aQ = r0 >> 6, sQ = r0 & 63;
  for (int it = 1; it < H_DIM; ++it){
    *(float4*)(&Qlds[aQ][sQ]) = make_float4(Qc[0], Qc[1], Qc[2], Qc[3]);
    __syncthreads();
    if (tid < 64){
      float m = -1e30f;
      #pragma unroll
      for (int aa = 0; aa < A_DIM; ++aa) m = fmaxf(m, Qlds[aa][lane]);
      float ss = 0.f;
      #pragma unroll
      for (int aa = 0; aa < A_DIM; ++aa) ss += __expf(Qlds[aa][lane] - m);
      Vs[lane] = m + __logf(ss);
    }
    __syncthreads();
    float hw = hs[it];
    #pragma unroll
    for (int rr = 0; rr < 4; ++rr){
      float accA = 0.f, accB = 0.f;
      #pragma unroll
      for (int q = 0; q < 16; ++q){
        float4 v = *(const float4*)(&Vs[4 * q]);
        accA = fmaf(Br[rr][q].x, v.x, fmaf(Br[rr][q].y, v.y, accA));
        accB = fmaf(Br[rr][q].z, v.z, fmaf(Br[rr][q].w, v.w, accB));
      }
      Qc[rr] = R[rr] + accA + accB;
      Qa[rr] = fmaf(hw, Qc[rr], Qa[rr]);
    }
  }
  *(float4*)(Qout + r0) = make_float4(Qa[0], Qa[1], Qa[2], Qa[3]);
}

// ---------------- fused HMM scan + logp_pi + logp_obs ----------------
__global__ __launch_bounds__(512, 2) void k_scan(const float* __restrict__ Bp,
                                                 const float* __restrict__ Qg,
                                                 const float* __restrict__ lo,
                                                 const float* __restrict__ lu,
                                                 const float* __restrict__ pa,
                                                 const float* __restrict__ Dlog,
                                                 float* __restrict__ out){
  const int n   = blockIdx.x;
  const int tid = threadIdx.x;
  const int g   = tid >> 6;     // wave 0..7, actions 2g, 2g+1
  const int j   = tid & 63;

  __shared__ __align__(16) float b_lds[2][S_DIM];
  __shared__ __align__(16) float part[8][S_DIM];
  __shared__ __align__(16) float Qlds[A_DIM][S_DIM + 1];

  for (int idx = tid; idx < A_DIM * S_DIM; idx += 512)
    Qlds[idx >> 6][idx & 63] = Qg[idx];

  { // b0 = softmax(D_logits), same for all n
    float dl = Dlog[j];
    float m = wmax(dl);
    float e = __expf(dl - m);
    float s = wsum(e);
    if (tid < 64) b_lds[0][j] = e / s;
  }

  // register-resident Bp columns for this thread's two actions
  float4 B0[16], B1[16];
  {
    const float* p0 = Bp + (2 * g) * S_DIM * S_DIM + j;
    const float* p1 = p0 + S_DIM * S_DIM;
    #pragma unroll
    for (int q = 0; q < 16; ++q){
      B0[q] = make_float4(p0[(4*q)*64], p0[(4*q+1)*64], p0[(4*q+2)*64], p0[(4*q+3)*64]);
      B1[q] = make_float4(p1[(4*q)*64], p1[(4*q+1)*64], p1[(4*q+2)*64], p1[(4*q+3)*64]);
    }
  }

  const float* pa_n = pa + n * A_DIM;   // step stride B*A = 1024
  const float* lo_n = lo + n * S_DIM;   // step stride B*S = 4096
  const float* lu_n = lu + n * A_DIM;
  float* out_pi  = out;
  float* out_obs = out + T_STEPS * BATCH;

  // prologue prefetch for t = 0
  float2 pa_c = *(const float2*)(pa_n + 2 * g);
  float lo_c = 0.f, lu_c = 0.f, lo_use = 0.f, lo_hold = 0.f;
  if (g == 0) lo_c    = lo_n[j];
  if (g == 1) lu_c    = lu_n[j & 15];
  if (g == 2) lo_hold = lo_n[j];
  __syncthreads();

  int cur = 0;
  for (int t = 0; t < T_STEPS; ++t){
    const int nxt = cur ^ 1;
    const int tp  = (t + 1 < T_STEPS) ? (t + 1) : (T_STEPS - 1);
    // prefetch next step's per-wave data
    float2 pa_nx = *(const float2*)(pa_n + tp * 1024 + 2 * g);
    float lo_nx = 0.f, lu_nx = 0.f, lo_hnx = 0.f;
    if (g == 0) lo_nx  = lo_n[tp * 4096 + j];
    if (g == 1) lu_nx  = lu_n[tp * 1024 + (j & 15)];
    if (g == 2) lo_hnx = lo_n[tp * 4096 + j];

    // ---- phase 1: partial priors ----
    float a0x = 0.f, a0y = 0.f, a0z = 0.f, a0w = 0.f;
    float a1x = 0.f, a1y = 0.f, a1z = 0.f, a1w = 0.f;
    #pragma unroll
    for (int q = 0; q < 16; ++q){
      const float4 bv = *(const float4*)(&b_lds[cur][4 * q]);
      a0x = fmaf(B0[q].x, bv.x, a0x); a0y = fmaf(B0[q].y, bv.y, a0y);
      a0z = fmaf(B0[q].z, bv.z, a0z); a0w = fmaf(B0[q].w, bv.w, a0w);
      a1x = fmaf(B1[q].x, bv.x, a1x); a1y = fmaf(B1[q].y, bv.y, a1y);
      a1z = fmaf(B1[q].z, bv.z, a1z); a1w = fmaf(B1[q].w, bv.w, a1w);
    }
    float va0 = (a0x + a0y) + (a0z + a0w);
    float va1 = (a1x + a1y) + (a1z + a1w);
    part[g][j] = pa_c.x * va0 + pa_c.y * va1;
    __syncthreads();   // A

    // ---- phase 2 ----
    if (g == 0){
      float prior = ((part[0][j] + part[1][j]) + (part[2][j] + part[3][j]))
                  + ((part[4][j] + part[5][j]) + (part[6][j] + part[7][j]));
      float mo   = wmax(lo_c);
      float lik  = __expf(lo_c - mo);
      float post = lik * prior;
      float ssum = wsum(post);
      b_lds[nxt][j] = post / ssum;
    } else if (g == 1){
      const int a = j & 15, s0 = (j >> 4) << 4;
      float Gp = 0.f;
      #pragma unroll
      for (int ss = 0; ss < 16; ++ss) Gp = fmaf(b_lds[cur][s0 + ss], Qlds[a][s0 + ss], Gp);
      Gp += __shfl_xor(Gp, 16, 64);
      Gp += __shfl_xor(Gp, 32, 64);   // every lane: full G[a], a = j&15
      float x1 = Gp + lu_c;
      float m1 = x1, m0 = Gp;
      #pragma unroll
      for (int o = 1; o < 16; o <<= 1){
        m1 = fmaxf(m1, __shfl_xor(m1, o, 64));
        m0 = fmaxf(m0, __shfl_xor(m0, o, 64));
      }
      float e1 = __expf(x1 - m1), e0 = __expf(Gp - m0);
      #pragma unroll
      for (int o = 1; o < 16; o <<= 1){
        e1 += __shfl_xor(e1, o, 64);
        e0 += __shfl_xor(e0, o, 64);
      }
      if (j == 0) out_pi[t * BATCH + n] = (m1 + __logf(e1)) - (m0 + __logf(e0));
    } else if (g == 2){
      if (t > 0){
        float term = __logf(b_lds[cur][j] + 1e-6f) * lo_use;
        float mm = wmax(term);
        float ee = wsum(__expf(term - mm));
        if (j == 0) out_obs[(t - 1) * BATCH + n] = mm + __logf(ee);
      }
    }
    __syncthreads();   // B

    pa_c = pa_nx;
    if (g == 0) lo_c = lo_nx;
    if (g == 1) lu_c = lu_nx;
    if (g == 2){ lo_use = lo_hold; lo_hold = lo_hnx; }
    cur = nxt;
  }
  // final logp_obs[T-1]
  if (g == 2){
    float term = __logf(b_lds[cur][j] + 1e-6f) * lo_use;
    float mm = wmax(term);
    float ee = wsum(__expf(term - mm));
    if (j == 0) out_obs[(T_STEPS - 1) * BATCH + n] = mm + __logf(ee);
  }
}

extern "C" void kernel_launch(void* const* d_in, const int* in_sizes, int n_in,
                              void* d_out, int out_size, void* d_ws, size_t ws_size,
                              hipStream_t stream){
  const float* o      = (const float*)d_in[0];
  const float* u      = (const float*)d_in[1];
  const float* obs_mu = (const float*)d_in[2];
  const float* obs_lv = (const float*)d_in[3];
  const float* obs_tl = (const float*)d_in[4];
  const float* ctl_mu = (const float*)d_in[5];
  const float* ctl_lv = (const float*)d_in[6];
  const float* ctl_tl = (const float*)d_in[7];
  const float* Blog   = (const float*)d_in[8];
  const float* Dlog   = (const float*)d_in[9];
  const float* Clog   = (const float*)d_in[10];
  const float* tau    = (const float*)d_in[11];
  float* out = (float*)d_out;
  float* ws  = (float*)d_ws;

  float* Bp = ws;                    // 65536
  float* Q  = ws + 65536;            // 1024
  float* lo = ws + 66560;            // 2,048,000
  float* lu = ws + 2114560;          // 512,000
  float* pa = ws + 2626560;          // 512,000  (total ~12.0 MiB)

  k_bp    <<<256, 256, 0, stream>>>(Blog, Bp);
  k_logp_o<<<dim3(64, 125), 256, 0, stream>>>(o, obs_mu, obs_lv, obs_tl, lo);
  k_logp_u<<<125, 256, 0, stream>>>(u, ctl_mu, ctl_lv, ctl_tl, lu, pa);
  k_vi    <<<1, 256, 0, stream>>>(Bp, obs_lv, Clog, tau, Q);
  k_scan  <<<64, 512, 0, stream>>>(Bp, Q, lo, lu, pa, Dlog, out);
}

// Round 2
// 572.034 us; speedup vs baseline: 1.3106x; 1.3106x over previous
//
#include <hip/hip_runtime.h>
#include <math.h>

#define T_STEPS 500
#define BATCH   64
#define S_DIM   64
#define A_DIM   16
#define OBS_D   32
#define CTL_D   8
#define H_DIM   30

#define LOG2PI 1.8378770664093453f

typedef float v2f __attribute__((ext_vector_type(2)));

__device__ __forceinline__ float wmax(float v){
  #pragma unroll
  for (int o = 32; o > 0; o >>= 1) v = fmaxf(v, __shfl_xor(v, o, 64));
  return v;
}
__device__ __forceinline__ float wsum(float v){
  #pragma unroll
  for (int o = 32; o > 0; o >>= 1) v += __shfl_xor(v, o, 64);
  return v;
}

// DPP add: v + dpp_move(v). CTRL is an immediate.
template<int CTRL>
__device__ __forceinline__ float dpp_add(float v){
  int x = __builtin_amdgcn_update_dpp(0, __float_as_int(v), CTRL, 0xF, 0xF, true);
  return v + __int_as_float(x);
}

// ---------------- k_pre: Bp softmax (blocks 0..255) + logp_u/p_a (blocks 256..380) ----------------
__global__ __launch_bounds__(256) void k_pre(const float* __restrict__ Blog,
                                             const float* __restrict__ u,
                                             const float* __restrict__ ctl_mu,
                                             const float* __restrict__ ctl_lv,
                                             const float* __restrict__ ctl_tl,
                                             float* __restrict__ Bp,
                                             float* __restrict__ lup,
                                             float* __restrict__ pap){
  const int tid = threadIdx.x;
  if (blockIdx.x < 256){
    const int row  = blockIdx.x * 4 + (tid >> 6);
    const int lane = tid & 63;
    float v = Blog[row * 64 + lane];
    float m = wmax(v);
    float e = __expf(v - m);
    float s = wsum(e);
    Bp[row * 64 + lane] = e / s;
    return;
  }
  const int item = (blockIdx.x - 256) * 256 + tid;   // 125*256 = 32000
  const float* up = u + item * CTL_D;
  float uu[CTL_D];
  #pragma unroll
  for (int i = 0; i < CTL_D; i += 4){
    float4 v = *(const float4*)(up + i);
    uu[i] = v.x; uu[i+1] = v.y; uu[i+2] = v.z; uu[i+3] = v.w;
  }
  float lp[A_DIM];
  #pragma unroll
  for (int a = 0; a < A_DIM; ++a){
    float z[CTL_D];
    float acc = 0.f, lvs = 0.f;
    #pragma unroll
    for (int i = 0; i < CTL_D; ++i){
      float lvv = ctl_lv[a * CTL_D + i];
      lvs += lvv;
      float s = uu[i] - ctl_mu[a * CTL_D + i];
      #pragma unroll
      for (int jj = 0; jj < i; ++jj) s = fmaf(-ctl_tl[a * 64 + i * CTL_D + jj], z[jj], s);
      z[i] = s * __expf(-lvv);
      acc  = fmaf(z[i], z[i], acc);
    }
    lp[a] = -0.5f * acc - lvs - 0.5f * CTL_D * LOG2PI;
  }
  float m = -1e30f;
  #pragma unroll
  for (int a = 0; a < A_DIM; ++a) m = fmaxf(m, lp[a]);
  float e[A_DIM], se = 0.f;
  #pragma unroll
  for (int a = 0; a < A_DIM; ++a){ e[a] = __expf(lp[a] - m); se += e[a]; }
  float inv = 1.f / se;
  #pragma unroll
  for (int a = 0; a < A_DIM; ++a){
    lup[item * A_DIM + a] = lp[a];
    pap[item * A_DIM + a] = e[a] * inv;
  }
}

// ---------------- logp_o: forward substitution, L via wave-uniform (scalar) loads ----------------
__global__ __launch_bounds__(256) void k_logp_o(const float* __restrict__ o,
                                                const float* __restrict__ mu,
                                                const float* __restrict__ lv,
                                                const float* __restrict__ tl,
                                                float* __restrict__ lo_out){
  const int k = blockIdx.x;                     // uniform -> scalar loads below
  const float* __restrict__ Lk  = tl + k * OBS_D * OBS_D;
  const float* __restrict__ muk = mu + k * OBS_D;
  const float* __restrict__ lvk = lv + k * OBS_D;

  float dinv[OBS_D];
  float lvsum = 0.f;
  #pragma unroll
  for (int i = 0; i < OBS_D; ++i){
    float x = lvk[i];
    lvsum += x;
    dinv[i] = __expf(-x);
  }

  const int item = blockIdx.y * 256 + threadIdx.x;   // 125*256 = 32000
  const float* op = o + item * OBS_D;
  float d[OBS_D];
  #pragma unroll
  for (int i = 0; i < OBS_D; i += 4){
    float4 v = *(const float4*)(op + i);
    d[i]   = v.x - muk[i];
    d[i+1] = v.y - muk[i+1];
    d[i+2] = v.z - muk[i+2];
    d[i+3] = v.w - muk[i+3];
  }
  float z[OBS_D];
  float acc = 0.f;
  #pragma unroll
  for (int i = 0; i < OBS_D; ++i){
    float s0 = d[i], s1 = 0.f;
    #pragma unroll
    for (int jj = 0; jj + 1 < i; jj += 2){
      s0 = fmaf(-Lk[i * OBS_D + jj],     z[jj],     s0);
      s1 = fmaf(-Lk[i * OBS_D + jj + 1], z[jj + 1], s1);
    }
    if (i & 1) s0 = fmaf(-Lk[i * OBS_D + i - 1], z[i - 1], s0);
    float zz = (s0 + s1) * dinv[i];
    z[i] = zz;
    acc  = fmaf(zz, zz, acc);
  }
  lo_out[item * S_DIM + k] = -0.5f * acc - lvsum - 0.5f * OBS_D * LOG2PI;
}

// ---------------- k_aux: row max of lo (blocks 0..7999) + VI (block 8000) ----------------
__global__ __launch_bounds__(256, 1) void k_aux(const float* __restrict__ lo,
                                                float* __restrict__ mo,
                                                const float* __restrict__ Bp,
                                                const float* __restrict__ obs_lv,
                                                const float* __restrict__ Clog,
                                                const float* __restrict__ tau,
                                                float* __restrict__ Qout){
  const int tid  = threadIdx.x;
  const int lane = tid & 63;
  if (blockIdx.x < 8000){
    const int row = blockIdx.x * 4 + (tid >> 6);
    float v = lo[row * 64 + lane];
    float m = wmax(v);
    if (lane == 0) mo[row] = m;
    return;
  }
  // ---- VI ----
  __shared__ __align__(16) float Vs[S_DIM];
  __shared__ __align__(16) float Qlds[A_DIM][S_DIM];
  __shared__ float hs[H_DIM];

  float c  = Clog[lane];
  float cm = wmax(c);
  float cs = wsum(__expf(c - cm));
  float lseC = cm + __logf(cs);
  float sumLnCp = wsum(c) - 64.f * lseC;

  if (tid < 64){
    float t0   = tau[0];
    float rate = __expf(t0);
    float lg = 0.f;
    for (int i = 2; i <= lane; ++i) lg += __logf((float)i);
    float lh = (lane < H_DIM) ? ((float)lane * t0 - rate - lg) : -1e30f;
    float m  = wmax(lh);
    float e  = (lane < H_DIM) ? __expf(lh - m) : 0.f;
    float s  = wsum(e);
    if (lane < H_DIM) hs[lane] = e / s;
  }

  float4 Br[4][16];
  float R[4], Qc[4], Qa[4];
  const int r0 = tid * 4;
  #pragma unroll
  for (int rr = 0; rr < 4; ++rr){
    const float* p = Bp + (r0 + rr) * 64;
    float negentA = 0.f, negentB = 0.f;
    #pragma unroll
    for (int q = 0; q < 16; ++q){
      float4 v = *(const float4*)(p + 4 * q);
      Br[rr][q] = v;
      negentA = fmaf(v.x, __logf(v.x), fmaf(v.y, __logf(v.y), negentA));
      negentB = fmaf(v.z, __logf(v.z), fmaf(v.w, __logf(v.w), negentB));
    }
    int s = (r0 + rr) & 63;
    float oe = 0.f;
    const float* lvp = obs_lv + s * OBS_D;
    #pragma unroll
    for (int d = 0; d < OBS_D; d += 4){
      float4 v = *(const float4*)(lvp + d);
      oe += v.x + v.y + v.z + v.w;
    }
    oe += 0.5f * OBS_D * (1.f + LOG2PI);
    R[rr]  = -(negentA + negentB) + sumLnCp - oe;
    Qc[rr] = R[rr];
  }
  __syncthreads();
  #pragma unroll
  for (int rr = 0; rr < 4; ++rr) Qa[rr] = hs[0] * R[rr];

  const int aQ = r0 >> 6, sQ = r0 & 63;
  for (int it = 1; it < H_DIM; ++it){
    *(float4*)(&Qlds[aQ][sQ]) = make_float4(Qc[0], Qc[1], Qc[2], Qc[3]);
    __syncthreads();
    if (tid < 64){
      float m = -1e30f;
      #pragma unroll
      for (int aa = 0; aa < A_DIM; ++aa) m = fmaxf(m, Qlds[aa][lane]);
      float ss = 0.f;
      #pragma unroll
      for (int aa = 0; aa < A_DIM; ++aa) ss += __expf(Qlds[aa][lane] - m);
      Vs[lane] = m + __logf(ss);
    }
    __syncthreads();
    float hw = hs[it];
    #pragma unroll
    for (int rr = 0; rr < 4; ++rr){
      float accA = 0.f, accB = 0.f;
      #pragma unroll
      for (int q = 0; q < 16; ++q){
        float4 v = *(const float4*)(&Vs[4 * q]);
        accA = fmaf(Br[rr][q].x, v.x, fmaf(Br[rr][q].y, v.y, accA));
        accB = fmaf(Br[rr][q].z, v.z, fmaf(Br[rr][q].w, v.w, accB));
      }
      Qc[rr] = R[rr] + accA + accB;
      Qa[rr] = fmaf(hw, Qc[rr], Qa[rr]);
    }
  }
  *(float4*)(Qout + r0) = make_float4(Qa[0], Qa[1], Qa[2], Qa[3]);
}

// ---------------- fused HMM scan: belief only, one barrier/step, DPP reductions ----------------
// Lane layout: so = lane&7 (s-octant), jj = lane>>3, j = 8*wave + jj.
__global__ __launch_bounds__(512, 1) void k_scan(const float* __restrict__ Bp,
                                                 const float* __restrict__ lo,
                                                 const float* __restrict__ mo,
                                                 const float* __restrict__ pa,
                                                 const float* __restrict__ Dlog,
                                                 float* __restrict__ bseq){
  const int n   = blockIdx.x;
  const int tid = threadIdx.x;
  const int g   = tid >> 6;
  const int l   = tid & 63;
  const int so  = l & 7;
  const int jj  = l >> 3;
  const int j   = g * 8 + jj;

  __shared__ __align__(16) float b_lds[2][S_DIM];
  __shared__ __align__(16) float ps[2][8];

  // register-resident Bp: Bq[a][q] = Bp[a, 8so+2q .. +1, j]
  v2f Bq[16][4];
  #pragma unroll
  for (int a = 0; a < 16; ++a){
    #pragma unroll
    for (int q = 0; q < 4; ++q){
      int s = 8 * so + 2 * q;
      v2f t;
      t.x = Bp[a * 4096 + s * 64 + j];
      t.y = Bp[a * 4096 + (s + 1) * 64 + j];
      Bq[a][q] = t;
    }
  }

  if (tid < 64){
    float dl = Dlog[l];
    float m = wmax(dl);
    float e = __expf(dl - m);
    float s = wsum(e);
    float b0 = e / s;
    b_lds[0][l] = b0;
    bseq[n * 64 + l] = b0;
  }
  if (tid < 8) ps[0][tid] = 0.125f;

  const float* lo_n = lo + n * 64;     // + t*4096 + j
  const float* mo_n = mo + n;          // + t*64
  const float* pa_n = pa + n * 16;     // + t*1024 + a

  float loc = lo_n[j];
  float lon = lo_n[4096 + j];
  float moc = mo_n[0];
  float mon = mo_n[64];
  float pac[16], pan[16];
  #pragma unroll
  for (int a = 0; a < 16; ++a){ pac[a] = pa_n[a]; pan[a] = pa_n[1024 + a]; }

  __syncthreads();

  int cur = 0;
  for (int t = 0; t < T_STEPS; ++t){
    const int nxt = cur ^ 1;
    // scale from previous step's partial sums (broadcast reads)
    float4 p0 = *(const float4*)&ps[cur][0];
    float4 p1 = *(const float4*)&ps[cur][4];
    float sum = ((p0.x + p0.y) + (p0.z + p0.w)) + ((p1.x + p1.y) + (p1.z + p1.w));
    float lik = __expf(loc - moc) * __builtin_amdgcn_rcpf(sum);

    // belief tile for this lane's s-octant
    v2f b2[4];
    {
      float4 t0 = *(const float4*)&b_lds[cur][8 * so];
      float4 t1 = *(const float4*)&b_lds[cur][8 * so + 4];
      b2[0].x = t0.x; b2[0].y = t0.y;
      b2[1].x = t0.z; b2[1].y = t0.w;
      b2[2].x = t1.x; b2[2].y = t1.y;
      b2[3].x = t1.z; b2[3].y = t1.w;
    }

    v2f pri2; pri2.x = 0.f; pri2.y = 0.f;
    #pragma unroll
    for (int a = 0; a < 16; ++a){
      v2f acc = Bq[a][0] * b2[0];
      acc = __builtin_elementwise_fma(Bq[a][1], b2[1], acc);
      acc = __builtin_elementwise_fma(Bq[a][2], b2[2], acc);
      acc = __builtin_elementwise_fma(Bq[a][3], b2[3], acc);
      v2f pav; pav.x = pac[a]; pav.y = pac[a];
      pri2 = __builtin_elementwise_fma(pav, acc, pri2);
    }
    float pri = pri2.x + pri2.y;

    // butterfly over s-octants (lanes ^1,^2,^7) — all DPP, all lanes get full prior[j]
    pri = dpp_add<0xB1>(pri);    // quad_perm [1,0,3,2]  (xor 1)
    pri = dpp_add<0x4E>(pri);    // quad_perm [2,3,0,1]  (xor 2)
    pri = dpp_add<0x141>(pri);   // row_half_mirror      (xor 7)

    float post = pri * lik;
    if (so == 0){
      b_lds[nxt][j] = post;
      bseq[(t + 1) * 4096 + n * 64 + j] = post;
    }

    // per-wave sum over jj: ror8 then bcast ladder; lanes 48..63 hold wave total
    float w = post;
    w = dpp_add<0x128>(w);       // row_ror:8   (xor 8 within rows of 16)
    w = dpp_add<0x142>(w);       // row_bcast15
    w = dpp_add<0x143>(w);       // row_bcast31
    if (l == 48) ps[nxt][g] = w;

    // prefetch t+2
    int tp = (t + 2 <= T_STEPS - 1) ? (t + 2) : (T_STEPS - 1);
    loc = lon; lon = lo_n[tp * 4096 + j];
    moc = mon; mon = mo_n[tp * 64];
    #pragma unroll
    for (int a = 0; a < 16; ++a) pac[a] = pan[a];
    #pragma unroll
    for (int a = 0; a < 16; ++a) pan[a] = pa_n[tp * 1024 + a];

    __syncthreads();
    cur = nxt;
  }
}

// ---------------- epilogue: logp_pi + logp_obs, fully parallel over (t,n) ----------------
__global__ __launch_bounds__(256, 1) void k_out(const float* __restrict__ bseq,
                                                const float* __restrict__ Qg,
                                                const float* __restrict__ lo,
                                                const float* __restrict__ lu,
                                                float* __restrict__ out){
  __shared__ __align__(16) float Qs[A_DIM][S_DIM];
  const int tid = threadIdx.x;
  for (int i = tid; i < A_DIM * S_DIM; i += 256) Qs[i >> 6][i & 63] = Qg[i];
  __syncthreads();

  const int item = blockIdx.x * 256 + tid;   // t*64 + n
  float bs[64];
  const float* bp_ = bseq + item * 64;
  float bsum = 0.f;
  #pragma unroll
  for (int i = 0; i < 16; ++i){
    float4 v = *(const float4*)(bp_ + 4 * i);
    bs[4*i] = v.x; bs[4*i+1] = v.y; bs[4*i+2] = v.z; bs[4*i+3] = v.w;
    bsum += (v.x + v.y) + (v.z + v.w);
  }
  float binv = 1.0f / bsum;

  float G[A_DIM];
  #pragma unroll
  for (int a = 0; a < A_DIM; ++a){
    float acc = 0.f;
    #pragma unroll
    for (int s = 0; s < 64; ++s) acc = fmaf(bs[s], Qs[a][s], acc);
    G[a] = acc * binv;
  }
  const float* lup = lu + item * A_DIM;
  float m1 = -1e30f, m0 = -1e30f;
  float x1[A_DIM];
  #pragma unroll
  for (int a = 0; a < A_DIM; ++a){
    x1[a] = G[a] + lup[a];
    m1 = fmaxf(m1, x1[a]);
    m0 = fmaxf(m0, G[a]);
  }
  float e1 = 0.f, e0 = 0.f;
  #pragma unroll
  for (int a = 0; a < A_DIM; ++a){
    e1 += __expf(x1[a] - m1);
    e0 += __expf(G[a] - m0);
  }
  out[item] = (m1 + __logf(e1)) - (m0 + __logf(e0));

  // logp_obs: uses b[t+1] and lo[t]
  const float* bq = bseq + (item + 64) * 64;
  float bsum2 = 0.f;
  #pragma unroll
  for (int i = 0; i < 16; ++i){
    float4 v = *(const float4*)(bq + 4 * i);
    bs[4*i] = v.x; bs[4*i+1] = v.y; bs[4*i+2] = v.z; bs[4*i+3] = v.w;
    bsum2 += (v.x + v.y) + (v.z + v.w);
  }
  float inv2 = 1.0f / bsum2;
  const float* lop = lo + item * 64;
  float terms[64];
  float mt = -1e30f;
  #pragma unroll
  for (int i = 0; i < 16; ++i){
    float4 v = *(const float4*)(lop + 4 * i);
    float t0 = __logf(bs[4*i]   * inv2 + 1e-6f) * v.x;
    float t1 = __logf(bs[4*i+1] * inv2 + 1e-6f) * v.y;
    float t2 = __logf(bs[4*i+2] * inv2 + 1e-6f) * v.z;
    float t3 = __logf(bs[4*i+3] * inv2 + 1e-6f) * v.w;
    terms[4*i] = t0; terms[4*i+1] = t1; terms[4*i+2] = t2; terms[4*i+3] = t3;
    mt = fmaxf(mt, fmaxf(fmaxf(t0, t1), fmaxf(t2, t3)));
  }
  float es = 0.f;
  #pragma unroll
  for (int s = 0; s < 64; ++s) es += __expf(terms[s] - mt);
  out[T_STEPS * BATCH + item] = mt + __logf(es);
}

extern "C" void kernel_launch(void* const* d_in, const int* in_sizes, int n_in,
                              void* d_out, int out_size, void* d_ws, size_t ws_size,
                              hipStream_t stream){
  const float* o      = (const float*)d_in[0];
  const float* u      = (const float*)d_in[1];
  const float* obs_mu = (const float*)d_in[2];
  const float* obs_lv = (const float*)d_in[3];
  const float* obs_tl = (const float*)d_in[4];
  const float* ctl_mu = (const float*)d_in[5];
  const float* ctl_lv = (const float*)d_in[6];
  const float* ctl_tl = (const float*)d_in[7];
  const float* Blog   = (const float*)d_in[8];
  const float* Dlog   = (const float*)d_in[9];
  const float* Clog   = (const float*)d_in[10];
  const float* tau    = (const float*)d_in[11];
  float* out = (float*)d_out;
  float* ws  = (float*)d_ws;

  float* Bp   = ws;                    // 65536
  float* Q    = ws + 65536;            // 1024
  float* lo   = ws + 66560;            // 2,048,000
  float* lu   = ws + 2114560;          // 512,000
  float* pa   = ws + 2626560;          // 512,000
  float* mo   = ws + 3138560;          // 32,000
  float* bseq = ws + 3170560;          // 501*4096 = 2,052,096   (total ~20.9 MiB)

  k_pre   <<<381, 256, 0, stream>>>(Blog, u, ctl_mu, ctl_lv, ctl_tl, Bp, lu, pa);
  k_logp_o<<<dim3(64, 125), 256, 0, stream>>>(o, obs_mu, obs_lv, obs_tl, lo);
  k_aux   <<<8001, 256, 0, stream>>>(lo, mo, Bp, obs_lv, Clog, tau, Q);
  k_scan  <<<64, 512, 0, stream>>>(Bp, lo, mo, pa, Dlog, bseq);
  k_out   <<<125, 256, 0, stream>>>(bseq, Q, lo, lu, out);
}